// Round 1
// baseline (482.490 us; speedup 1.0000x reference)
//
#include <hip/hip_runtime.h>

// HMM forward scan, one workgroup per unit u. U=256, N=64, S=4, B=64, T=1024.
// Wave w owns batches [16w,16w+16); lane (q=lane>>4,l=lane&15) owns batch
// b=16w+l and the 16 states j = sig(jt, 4q+r).
//
// R9 (unnormalized recursion): per-step normalization removed. Identity:
// cumulative ll_t = log S^un_t (telescoping of log Ssum). We evolve the
// raw (hat) forward variable, capture raw sums ssraw into hist, and
// rescale Rv ONCE PER OCTET by an exact power of two f = 2^-k, with k
// from the exponent field of ssraw at octet slot 5 (2 steps of slack).
// ll_t = log(ssraw_t) + ln2 * sum(k applied before t). Consequences:
//  - E-MFMA no longer depends on the cross-lane reduce (be packed from
//    RAW x at load time; no rcp, no xs-mul, no e1/pe1 bookkeeping).
//  - reduce results have no in-loop consumer except the once-per-8
//    exponent read -> shfl lgkm waits sink freely.
//  - slot-7 consume deferred into next group's step 0 (tail-consume only
//    before a flush) -> once-per-8 exposed wait becomes once-per-32.
//  - flush has no prefix-sum: correction is constant within an octet.

#define U_ 256
#define N_ 64
#define S_ 4
#define B_ 64
#define T_ 1024
#define ROWP 72
#define LN2F 0.69314718055994530942f

typedef __attribute__((ext_vector_type(8))) __bf16 bf16x8;
typedef __attribute__((ext_vector_type(4))) float floatx4;

__device__ __forceinline__ int sig(int jt, int m) {
    return 32 * (jt >> 1) + 4 * (jt & 1) + 8 * (m >> 2) + (m & 3);
}

__launch_bounds__(256, 1)
__global__ void hmm_fwd_kernel(const float* __restrict__ xg,     // [B][T][S]
                               const float* __restrict__ trans,  // [U][N][N]
                               const float* __restrict__ emis,   // [U][N][S]
                               const float* __restrict__ initk,  // [U][N]
                               float* __restrict__ out)          // [B][T][U]
{
    __shared__ __bf16 AT[N_ * ROWP];
    __shared__ float BemS[N_][S_];
    __shared__ float IS[N_];

    const int bid = blockIdx.x;
    const int u = ((bid & 7) << 5) | (bid >> 3);   // XCD-aware u swizzle
    const int tid = threadIdx.x;
    const int lane = tid & 63;
    const int w = tid >> 6;
    const int q = lane >> 4;
    const int l = lane & 15;

    // ---------------- prologue: softmaxes (one-time) ----------------
    if (tid < 64) {
        const float* rowp = trans + (u * N_ + tid) * N_;
        float v[N_];
        #pragma unroll
        for (int k = 0; k < 16; ++k) {
            floatx4 t4 = *(const floatx4*)(rowp + 4 * k);
            v[4*k] = t4.x; v[4*k+1] = t4.y; v[4*k+2] = t4.z; v[4*k+3] = t4.w;
        }
        float m = v[0];
        #pragma unroll
        for (int j = 1; j < N_; ++j) m = fmaxf(m, v[j]);
        float s = 0.f;
        #pragma unroll
        for (int j = 0; j < N_; ++j) { v[j] = __expf(v[j] - m); s += v[j]; }
        float inv = 1.0f / s;
        #pragma unroll
        for (int j = 0; j < N_; ++j) AT[j * ROWP + tid] = (__bf16)(v[j] * inv);
    } else if (tid < 128) {
        int n = tid - 64;
        floatx4 e4 = *(const floatx4*)(emis + (u * N_ + n) * S_);
        float m = fmaxf(fmaxf(e4.x, e4.y), fmaxf(e4.z, e4.w));
        float a = __expf(e4.x - m), b2 = __expf(e4.y - m);
        float c = __expf(e4.z - m), d = __expf(e4.w - m);
        float inv = 1.0f / (a + b2 + c + d);
        BemS[n][0] = a*inv; BemS[n][1] = b2*inv; BemS[n][2] = c*inv; BemS[n][3] = d*inv;
    } else if (tid < 192) {
        int j = tid - 128;
        float v = initk[u * N_ + j];
        float m = v;
        #pragma unroll
        for (int s = 1; s < 64; s <<= 1) m = fmaxf(m, __shfl_xor(m, s, 64));
        float e = __expf(v - m);
        float ssum = e;
        #pragma unroll
        for (int s = 1; s < 64; s <<= 1) ssum += __shfl_xor(ssum, s, 64);
        IS[j] = e / ssum;
    }
    __syncthreads();

    // ------------- persistent register state -------------
    bf16x8 afrag[4][2];
    #pragma unroll
    for (int jt = 0; jt < 4; ++jt)
        #pragma unroll
        for (int kt = 0; kt < 2; ++kt)
            afrag[jt][kt] = *(const bf16x8*)&AT[sig(jt, l) * ROWP + 32*kt + 8*q];

    bf16x8 afragE[4];
    #pragma unroll
    for (int jt = 0; jt < 4; ++jt) {
        #pragma unroll
        for (int p = 0; p < 8; ++p) afragE[jt][p] = (__bf16)0.f;
        if (q == 0) {
            #pragma unroll
            for (int c = 0; c < 4; ++c)
                afragE[jt][c] = (__bf16)BemS[sig(jt, l)][c];
        }
    }

    floatx4 Rv[4];
    #pragma unroll
    for (int jt = 0; jt < 4; ++jt)
        #pragma unroll
        for (int r = 0; r < 4; ++r) Rv[jt][r] = IS[sig(jt, 4*q + r)];

    __asm__ volatile("" ::: "memory");   // pin LDS-sourced state in VGPRs

    const int b = 16*w + l;
    const float* xin = xg + b * (T_ * S_);
    float* llout = out + (size_t)b * T_ * U_ + u;

    const floatx4 z = {0.f, 0.f, 0.f, 0.f};
    floatx4 Ev[4];

    // pack raw x into an E-operand fragment (hi half zero: afragE K-rows
    // 4..31 are zero, so only K0..3 on q==0 lanes matter; zeros avoid NaN*0).
    auto packbe = [&](floatx4 x4) {
        bf16x8 t;
        t[0] = (__bf16)x4.x; t[1] = (__bf16)x4.y;
        t[2] = (__bf16)x4.z; t[3] = (__bf16)x4.w;
        t[4] = (__bf16)0.f;  t[5] = (__bf16)0.f;
        t[6] = (__bf16)0.f;  t[7] = (__bf16)0.f;
        return t;
    };

    // ---------------- pipeline fill ----------------
    {
        bf16x8 be0 = packbe(*(const floatx4*)xin);
        #pragma unroll
        for (int jt = 0; jt < 4; ++jt)
            Ev[jt] = __builtin_amdgcn_mfma_f32_16x16x32_bf16(afragE[jt], be0, z, 0, 0, 0);
    }
    bf16x8 beA[4], beB[4];
    #pragma unroll
    for (int i = 0; i < 4; ++i)
        beA[i] = packbe(*(const floatx4*)(xin + (1 + i) * S_));   // x_1..x_4

    float hist[8];
    float ssf = 1.0f;
    float pp0 = 0.f, pa16 = 0.f, pa32 = 0.f, pa48 = 0.f;
    float Cacc = 0.f;
    float kfv[4] = {0.f, 0.f, 0.f, 0.f};

    // consume step (slot kprev)'s shfl results: raw ss capture only.
    auto consume = [&](int kprev, bool o) {
        float ss = (pp0 + pa16) + (pa32 + pa48);
        hist[kprev] = o ? ss : hist[kprev];
        if (kprev == 5) ssf = ss;
    };

    // one HMM step. beS = packed raw x_{t+1}. No rcp, no xs scaling.
    auto step = [&](const bf16x8& beS, int slot, bool own, bool ownP) {
        // gv_t = Ev_t o Rv_t   (raw/hat forward variable)
        floatx4 gv[4];
        #pragma unroll
        for (int jt = 0; jt < 4; ++jt) gv[jt] = Ev[jt] * Rv[jt];

        // pack b_t
        bf16x8 bf0, bf1;
        #pragma unroll
        for (int p = 0; p < 4; ++p) {
            bf0[p]     = (__bf16)gv[0][p];
            bf0[4 + p] = (__bf16)gv[1][p];
            bf1[p]     = (__bf16)gv[2][p];
            bf1[4 + p] = (__bf16)gv[3][p];
        }

        // R_{t+1} = A^T b_t (chained C accumulation)
        #pragma unroll
        for (int jt = 0; jt < 4; ++jt) {
            floatx4 acc = __builtin_amdgcn_mfma_f32_16x16x32_bf16(afrag[jt][0], bf0, z, 0, 0, 0);
            Rv[jt] = __builtin_amdgcn_mfma_f32_16x16x32_bf16(afrag[jt][1], bf1, acc, 0, 0, 0);
        }

        // consume previous step's shfl results (after MFMA issue).
        // slot 0 consumes the previous group's slot 7 (deferred).
        if (slot == 0) consume(7, ownP); else consume(slot - 1, own);

        // Ev_{t+1} = B * x_{t+1}  (raw operand, no reduce dependency)
        #pragma unroll
        for (int jt = 0; jt < 4; ++jt)
            Ev[jt] = __builtin_amdgcn_mfma_f32_16x16x32_bf16(afragE[jt], beS, z, 0, 0, 0);

        // issue ss_t reduce last: in-lane adds + 3 parallel shfls
        floatx4 s4 = (gv[0] + gv[1]) + (gv[2] + gv[3]);
        pp0  = (s4.x + s4.y) + (s4.z + s4.w);
        pa16 = __shfl_xor(pp0, 16, 64);
        pa32 = __shfl_xor(pp0, 32, 64);
        pa48 = __shfl_xor(pp0, 48, 64);
    };

    // ---------------- T-loop: 32-step blocks of 4 octets ----------------
    for (int tbb = 0; tbb < T_; tbb += 32) {
        #pragma unroll
        for (int g = 0; g < 4; ++g) {
            const int tb = tbb + 8 * g;
            const bool own  = (q == g);
            const bool ownP = (q == ((g + 3) & 3));

            #pragma unroll
            for (int i = 0; i < 4; ++i) {
                int ti = tb + 5 + i; ti = (ti < T_) ? ti : T_ - 1;
                beB[i] = packbe(*(const floatx4*)(xin + ti * S_));
            }

            step(beA[0], 0, own, ownP); step(beA[1], 1, own, ownP);
            step(beA[2], 2, own, ownP); step(beA[3], 3, own, ownP);

            #pragma unroll
            for (int i = 0; i < 4; ++i) {
                int ti = tb + 9 + i; ti = (ti < T_) ? ti : T_ - 1;
                beA[i] = packbe(*(const floatx4*)(xin + ti * S_));
            }

            step(beB[0], 4, own, ownP); step(beB[1], 5, own, ownP);
            step(beB[2], 6, own, ownP); step(beB[3], 7, own, ownP);

            if (g == 3) consume(7, own);   // pre-flush tail (once per 32)

            // octet boundary: exact power-of-2 rescale of the hat-state.
            // f = 2^-k, k = unbiased exponent of ssraw_{slot5} (2-step slack).
            unsigned eb = (__float_as_uint(ssf) >> 23) & 255u;
            float f = __uint_as_float((254u - eb) << 23);
            #pragma unroll
            for (int jt = 0; jt < 4; ++jt) Rv[jt] *= f;
            kfv[g] = (float)((int)eb - 127);
        }

        // ---------------- flush: ll_t = log(ssraw_t) + ln2 * sum(k) ------
        float s01  = kfv[0] + kfv[1];
        float s012 = s01 + kfv[2];
        float offk = (q == 1) ? kfv[0] : ((q == 2) ? s01 : ((q == 3) ? s012 : 0.f));
        float base = Cacc + LN2F * offk;
        float* fp = llout + (size_t)(tbb + 8 * q) * U_;
        #pragma unroll
        for (int k = 0; k < 8; ++k)
            fp[(size_t)k * U_] = __logf(hist[k]) + base;
        Cacc += LN2F * (s012 + kfv[3]);
    }
}

extern "C" void kernel_launch(void* const* d_in, const int* in_sizes, int n_in,
                              void* d_out, int out_size, void* d_ws, size_t ws_size,
                              hipStream_t stream) {
    const float* xg    = (const float*)d_in[0];
    const float* trans = (const float*)d_in[1];
    const float* emis  = (const float*)d_in[2];
    const float* initk = (const float*)d_in[3];
    float* out = (float*)d_out;
    hipLaunchKernelGGL(hmm_fwd_kernel, dim3(U_), dim3(256), 0, stream,
                       xg, trans, emis, initk, out);
}

// Round 2
// 363.762 us; speedup vs baseline: 1.3264x; 1.3264x over previous
//
#include <hip/hip_runtime.h>

// HMM forward scan, one workgroup per unit u. U=256, N=64, S=4, B=64, T=1024.
// Wave w owns batches [16w,16w+16); lane (q=lane>>4,l=lane&15) owns batch
// b=16w+l and the 16 states j = sig(jt, 4q+r).
//
// R10 = R9 algorithm (unnormalized recursion, exact pow2 octet rescale,
// raw-x E-operands, deferred slot-7 consume) + R8 loop structure.
// R9's 4x outer unroll spilled (VGPR 96->256, WRITE_SIZE 65->530MB,
// scratch-bound). Fixes:
//  - octet loop NOT unrolled (#pragma unroll 1), one octet per iteration;
//  - kfv[4] runtime-indexed array replaced by incremental scalar
//    accumulators offacc/sumk (rule: runtime-indexed arrays -> scratch);
//  - flush per 32 steps, prefix-sum-free: ll = log(hist) + Cacc + ln2*offacc.
//
// Identity: ll_t = log(ssraw_t) + ln2 * sum(k applied before t), where the
// hat-state is rescaled by exactly f = 2^-k once per octet (k from the
// exponent of ssraw at octet slot 5; 2 steps of slack before use).

#define U_ 256
#define N_ 64
#define S_ 4
#define B_ 64
#define T_ 1024
#define ROWP 72
#define LN2F 0.69314718055994530942f

typedef __attribute__((ext_vector_type(8))) __bf16 bf16x8;
typedef __attribute__((ext_vector_type(4))) float floatx4;

__device__ __forceinline__ int sig(int jt, int m) {
    return 32 * (jt >> 1) + 4 * (jt & 1) + 8 * (m >> 2) + (m & 3);
}

__launch_bounds__(256, 1)
__global__ void hmm_fwd_kernel(const float* __restrict__ xg,     // [B][T][S]
                               const float* __restrict__ trans,  // [U][N][N]
                               const float* __restrict__ emis,   // [U][N][S]
                               const float* __restrict__ initk,  // [U][N]
                               float* __restrict__ out)          // [B][T][U]
{
    __shared__ __bf16 AT[N_ * ROWP];
    __shared__ float BemS[N_][S_];
    __shared__ float IS[N_];

    const int bid = blockIdx.x;
    const int u = ((bid & 7) << 5) | (bid >> 3);   // XCD-aware u swizzle
    const int tid = threadIdx.x;
    const int lane = tid & 63;
    const int w = tid >> 6;
    const int q = lane >> 4;
    const int l = lane & 15;

    // ---------------- prologue: softmaxes (one-time) ----------------
    if (tid < 64) {
        const float* rowp = trans + (u * N_ + tid) * N_;
        float v[N_];
        #pragma unroll
        for (int k = 0; k < 16; ++k) {
            floatx4 t4 = *(const floatx4*)(rowp + 4 * k);
            v[4*k] = t4.x; v[4*k+1] = t4.y; v[4*k+2] = t4.z; v[4*k+3] = t4.w;
        }
        float m = v[0];
        #pragma unroll
        for (int j = 1; j < N_; ++j) m = fmaxf(m, v[j]);
        float s = 0.f;
        #pragma unroll
        for (int j = 0; j < N_; ++j) { v[j] = __expf(v[j] - m); s += v[j]; }
        float inv = 1.0f / s;
        #pragma unroll
        for (int j = 0; j < N_; ++j) AT[j * ROWP + tid] = (__bf16)(v[j] * inv);
    } else if (tid < 128) {
        int n = tid - 64;
        floatx4 e4 = *(const floatx4*)(emis + (u * N_ + n) * S_);
        float m = fmaxf(fmaxf(e4.x, e4.y), fmaxf(e4.z, e4.w));
        float a = __expf(e4.x - m), b2 = __expf(e4.y - m);
        float c = __expf(e4.z - m), d = __expf(e4.w - m);
        float inv = 1.0f / (a + b2 + c + d);
        BemS[n][0] = a*inv; BemS[n][1] = b2*inv; BemS[n][2] = c*inv; BemS[n][3] = d*inv;
    } else if (tid < 192) {
        int j = tid - 128;
        float v = initk[u * N_ + j];
        float m = v;
        #pragma unroll
        for (int s = 1; s < 64; s <<= 1) m = fmaxf(m, __shfl_xor(m, s, 64));
        float e = __expf(v - m);
        float ssum = e;
        #pragma unroll
        for (int s = 1; s < 64; s <<= 1) ssum += __shfl_xor(ssum, s, 64);
        IS[j] = e / ssum;
    }
    __syncthreads();

    // ------------- persistent register state -------------
    bf16x8 afrag[4][2];
    #pragma unroll
    for (int jt = 0; jt < 4; ++jt)
        #pragma unroll
        for (int kt = 0; kt < 2; ++kt)
            afrag[jt][kt] = *(const bf16x8*)&AT[sig(jt, l) * ROWP + 32*kt + 8*q];

    bf16x8 afragE[4];
    #pragma unroll
    for (int jt = 0; jt < 4; ++jt) {
        #pragma unroll
        for (int p = 0; p < 8; ++p) afragE[jt][p] = (__bf16)0.f;
        if (q == 0) {
            #pragma unroll
            for (int c = 0; c < 4; ++c)
                afragE[jt][c] = (__bf16)BemS[sig(jt, l)][c];
        }
    }

    floatx4 Rv[4];
    #pragma unroll
    for (int jt = 0; jt < 4; ++jt)
        #pragma unroll
        for (int r = 0; r < 4; ++r) Rv[jt][r] = IS[sig(jt, 4*q + r)];

    __asm__ volatile("" ::: "memory");   // pin LDS-sourced state in VGPRs

    const int b = 16*w + l;
    const float* xin = xg + b * (T_ * S_);
    float* llout = out + (size_t)b * T_ * U_ + u;

    const floatx4 z = {0.f, 0.f, 0.f, 0.f};
    floatx4 Ev[4];

    // pack raw x into an E-operand fragment (hi half zero: afragE K-rows
    // 4..31 are zero on all lanes, so the garbage-free zero hi half is safe).
    auto packbe = [&](floatx4 x4) {
        bf16x8 t;
        t[0] = (__bf16)x4.x; t[1] = (__bf16)x4.y;
        t[2] = (__bf16)x4.z; t[3] = (__bf16)x4.w;
        t[4] = (__bf16)0.f;  t[5] = (__bf16)0.f;
        t[6] = (__bf16)0.f;  t[7] = (__bf16)0.f;
        return t;
    };

    // ---------------- pipeline fill ----------------
    {
        bf16x8 be0 = packbe(*(const floatx4*)xin);
        #pragma unroll
        for (int jt = 0; jt < 4; ++jt)
            Ev[jt] = __builtin_amdgcn_mfma_f32_16x16x32_bf16(afragE[jt], be0, z, 0, 0, 0);
    }
    bf16x8 beA[4], beB[4];
    #pragma unroll
    for (int i = 0; i < 4; ++i)
        beA[i] = packbe(*(const floatx4*)(xin + (1 + i) * S_));   // x_1..x_4

    float hist[8];
    float ssf = 1.0f;
    float pp0 = 0.f, pa16 = 0.f, pa32 = 0.f, pa48 = 0.f;
    float Cacc = 0.f;
    float offacc = 0.f, sumk = 0.f;

    // consume step (slot kprev)'s shfl results: raw ss capture only.
    auto consume = [&](int kprev, bool o) {
        float ss = (pp0 + pa16) + (pa32 + pa48);
        hist[kprev] = o ? ss : hist[kprev];
        if (kprev == 5) ssf = ss;
    };

    // one HMM step. beS = packed raw x_{t+1}. No rcp, no xs scaling.
    auto step = [&](const bf16x8& beS, int slot, bool own, bool ownP) {
        // gv_t = Ev_t o Rv_t   (raw/hat forward variable)
        floatx4 gv[4];
        #pragma unroll
        for (int jt = 0; jt < 4; ++jt) gv[jt] = Ev[jt] * Rv[jt];

        // pack b_t
        bf16x8 bf0, bf1;
        #pragma unroll
        for (int p = 0; p < 4; ++p) {
            bf0[p]     = (__bf16)gv[0][p];
            bf0[4 + p] = (__bf16)gv[1][p];
            bf1[p]     = (__bf16)gv[2][p];
            bf1[4 + p] = (__bf16)gv[3][p];
        }

        // R_{t+1} = A^T b_t (chained C accumulation)
        #pragma unroll
        for (int jt = 0; jt < 4; ++jt) {
            floatx4 acc = __builtin_amdgcn_mfma_f32_16x16x32_bf16(afrag[jt][0], bf0, z, 0, 0, 0);
            Rv[jt] = __builtin_amdgcn_mfma_f32_16x16x32_bf16(afrag[jt][1], bf1, acc, 0, 0, 0);
        }

        // consume previous step's shfl results (after MFMA issue).
        // slot 0 consumes the previous octet's slot 7 (deferred).
        if (slot == 0) consume(7, ownP); else consume(slot - 1, own);

        // Ev_{t+1} = B * x_{t+1}  (raw operand, no reduce dependency)
        #pragma unroll
        for (int jt = 0; jt < 4; ++jt)
            Ev[jt] = __builtin_amdgcn_mfma_f32_16x16x32_bf16(afragE[jt], beS, z, 0, 0, 0);

        // issue ss_t reduce last: in-lane adds + 3 parallel shfls
        floatx4 s4 = (gv[0] + gv[1]) + (gv[2] + gv[3]);
        pp0  = (s4.x + s4.y) + (s4.z + s4.w);
        pa16 = __shfl_xor(pp0, 16, 64);
        pa32 = __shfl_xor(pp0, 32, 64);
        pa48 = __shfl_xor(pp0, 48, 64);
    };

    // ---------------- T-loop: one octet per iteration ----------------
    #pragma unroll 1
    for (int tb = 0; tb < T_; tb += 8) {
        const int oct = (tb >> 3) & 3;
        const bool own  = (q == oct);
        const bool ownP = (q == ((oct + 3) & 3));

        #pragma unroll
        for (int i = 0; i < 4; ++i) {
            int ti = tb + 5 + i; ti = (ti < T_) ? ti : T_ - 1;
            beB[i] = packbe(*(const floatx4*)(xin + ti * S_));
        }

        step(beA[0], 0, own, ownP); step(beA[1], 1, own, ownP);
        step(beA[2], 2, own, ownP); step(beA[3], 3, own, ownP);

        #pragma unroll
        for (int i = 0; i < 4; ++i) {
            int ti = tb + 9 + i; ti = (ti < T_) ? ti : T_ - 1;
            beA[i] = packbe(*(const floatx4*)(xin + ti * S_));
        }

        step(beB[0], 4, own, ownP); step(beB[1], 5, own, ownP);
        step(beB[2], 6, own, ownP); step(beB[3], 7, own, ownP);

        if (oct == 3) consume(7, own);   // pre-flush tail (once per 32)

        // octet boundary: exact power-of-2 rescale of the hat-state.
        // f = 2^-k, k = unbiased exponent of ssraw_{slot5} (2-step slack).
        {
            unsigned eb = (__float_as_uint(ssf) >> 23) & 255u;
            float f = __uint_as_float((254u - eb) << 23);
            #pragma unroll
            for (int jt = 0; jt < 4; ++jt) Rv[jt] *= f;
            float kf = (float)((int)eb - 127);
            offacc += (q > oct) ? kf : 0.f;   // octets before lane q's octet
            sumk   += kf;
        }

        // ---------------- flush: ll_t = log(ssraw_t) + correction -------
        if (oct == 3) {
            float base = Cacc + LN2F * offacc;
            float* fp = llout + (size_t)(tb - 24 + 8 * q) * U_;
            #pragma unroll
            for (int k = 0; k < 8; ++k)
                fp[(size_t)k * U_] = __logf(hist[k]) + base;
            Cacc += LN2F * sumk;
            offacc = 0.f; sumk = 0.f;
        }
    }
}

extern "C" void kernel_launch(void* const* d_in, const int* in_sizes, int n_in,
                              void* d_out, int out_size, void* d_ws, size_t ws_size,
                              hipStream_t stream) {
    const float* xg    = (const float*)d_in[0];
    const float* trans = (const float*)d_in[1];
    const float* emis  = (const float*)d_in[2];
    const float* initk = (const float*)d_in[3];
    float* out = (float*)d_out;
    hipLaunchKernelGGL(hmm_fwd_kernel, dim3(U_), dim3(256), 0, stream,
                       xg, trans, emis, initk, out);
}